// Round 5
// baseline (201.153 us; speedup 1.0000x reference)
//
#include <hip/hip_runtime.h>

// Problem constants: B=8, C=3, T=16, H=W=224, P0=2, P=16, FC=2
#define Bd 8
#define Cd 3
#define Td 16
#define Hd 224
#define Wd 224
#define Nd 1568            // (T/2)*(H/16)*(W/16)
#define Dd 1024            // 2*16*16*2
#define HWd (Hd*Wd)        // 50176
#define MASK_N (Bd*Nd)     // 12544
#define PATCH_ELEMS 1536.0

#define WIN 24             // 16x16 patch + 4 halo each side
#define PITCH 24           // no pad: rows 96B apart; float4-aligned; conflicts <=2-way
#define PLANE (WIN*PITCH)  // 576 floats
#define BUF (6*PLANE)      // 3456 floats per double-buffer half (13824 B)
#define GRID_MAIN 1024
#define STG_V4 864         // 6 planes * 24 rows * 6 float4 per row

struct TokGeo { int b, t2, ph, pw, WX, WY; };

__device__ __forceinline__ TokGeo geo(int tk) {
    TokGeo g;
    g.b = tk / Nd;
    int n = tk - g.b * Nd;
    g.t2 = n / 196;
    int rem = n - g.t2 * 196;
    g.ph = rem / 14;
    g.pw = rem - g.ph * 14;
    g.WX = min(max(g.pw * 16 - 4, 0), Wd - WIN);   // multiple of 4 -> float4 ok
    g.WY = min(max(g.ph * 16 - 4, 0), Hd - WIN);
    return g;
}

// global -> registers (keeps loads outstanding during compute)
__device__ __forceinline__ void stage_issue(const float* __restrict__ raw,
                                            const TokGeo& g, int tid,
                                            float4* st, int* loff) {
    const float* base = raw + ((size_t)g.b * 48 + (size_t)g.t2 * 2) * HWd;
    #pragma unroll
    for (int k = 0; k < 4; ++k) {
        int j = tid + k * 256;
        if (j < STG_V4) {
            int p   = j / 144;            // plane = c*2 + i0
            int rem = j - p * 144;
            int r   = rem / 6;
            int c4  = (rem - r * 6) << 2;
            const float* src = base + (p >> 1) * (16 * HWd) + (p & 1) * HWd
                             + (g.WY + r) * Wd + g.WX + c4;
            st[k] = *(const float4*)src;
            loff[k] = p * PLANE + r * PITCH + c4;
        } else {
            loff[k] = -1;
        }
    }
}

// registers -> LDS
__device__ __forceinline__ void stage_commit(float* __restrict__ dst,
                                             const float4* st, const int* loff) {
    #pragma unroll
    for (int k = 0; k < 4; ++k)
        if (loff[k] >= 0) *(float4*)(dst + loff[k]) = st[k];
}

__device__ __forceinline__ float compute_tok(const float* __restrict__ raw,
                                             const float* __restrict__ pl0,  // buffer base
                                             const TokGeo& g, int tid,
                                             float2 f0, float2 f1) {
    const int i1 = tid >> 4, i2 = tid & 15;
    const int h = (g.ph << 4) + i1;
    const int w = (g.pw << 4) + i2;
    const int tIdx = (h - g.WY) * PITCH + (w - g.WX);
    float acc = 0.f;
    #pragma unroll
    for (int i0 = 0; i0 < 2; ++i0) {
        float2 f = i0 ? f1 : f0;
        float mx = f.x + (float)w;
        float my = f.y + (float)h;

        float x0 = floorf(mx), y0 = floorf(my);
        float wx = mx - x0,    wy = my - y0;
        int x0i = (int)x0, y0i = (int)y0;
        int x1i = x0i + 1, y1i = y0i + 1;

        bool vx0 = (x0i >= 0) && (x0i < Wd);
        bool vx1 = (x1i >= 0) && (x1i < Wd);
        bool vy0 = (y0i >= 0) && (y0i < Hd);
        bool vy1 = (y1i >= 0) && (y1i < Hd);

        int xc0 = min(max(x0i, 0), Wd - 1);
        int xc1 = min(max(x1i, 0), Wd - 1);
        int yc0 = min(max(y0i, 0), Hd - 1);
        int yc1 = min(max(y1i, 0), Hd - 1);

        float w00 = (1.f - wx) * (1.f - wy) * ((vx0 && vy0) ? 1.f : 0.f);
        float w01 = wx         * (1.f - wy) * ((vx1 && vy0) ? 1.f : 0.f);
        float w10 = (1.f - wx) * wy         * ((vx0 && vy1) ? 1.f : 0.f);
        float w11 = wx         * wy         * ((vx1 && vy1) ? 1.f : 0.f);

        const int lx0 = xc0 - g.WX, lx1 = xc1 - g.WX;
        const int ly0 = yc0 - g.WY, ly1 = yc1 - g.WY;
        const bool ok = (lx0 >= 0) & (lx1 < WIN) & (ly0 >= 0) & (ly1 < WIN);

        if (ok) {
            const int b00 = ly0 * PITCH + lx0;
            const int b01 = ly0 * PITCH + lx1;
            const int b10 = ly1 * PITCH + lx0;
            const int b11 = ly1 * PITCH + lx1;
            #pragma unroll
            for (int c = 0; c < Cd; ++c) {
                const float* pl = pl0 + ((c << 1) | i0) * PLANE;
                float rec = pl[b00] * w00 + pl[b01] * w01
                          + pl[b10] * w10 + pl[b11] * w11;
                float d = rec - pl[tIdx];
                acc += d * d;
            }
        } else {   // sample escaped +-4 halo: ~6e-5 probability, execz-skipped
            const int i00 = yc0 * Wd + xc0;
            const int i01 = yc0 * Wd + xc1;
            const int i10 = yc1 * Wd + xc0;
            const int i11 = yc1 * Wd + xc1;
            const float* base = raw + ((size_t)g.b * 48 + (size_t)g.t2 * 2 + i0) * HWd;
            #pragma unroll
            for (int c = 0; c < Cd; ++c) {
                const float* img = base + c * (16 * HWd);
                float rec = img[i00] * w00 + img[i01] * w01
                          + img[i10] * w10 + img[i11] * w11;
                const float* pl = pl0 + ((c << 1) | i0) * PLANE;
                float d = rec - pl[tIdx];
                acc += d * d;
            }
        }
    }
    return acc;
}

// ---------------- compaction: active token list ----------------
__global__ void compact_kernel(const int* __restrict__ mask,
                               int* __restrict__ list,
                               unsigned int* __restrict__ cnt) {
    int i = blockIdx.x * 256 + threadIdx.x;
    bool m = (i < MASK_N) && (mask[i] != 0);
    unsigned long long bal = __ballot(m);
    int lane = threadIdx.x & 63;
    int wid  = threadIdx.x >> 6;
    unsigned pre  = (unsigned)__popcll(bal & ((1ull << lane) - 1ull));
    unsigned wtot = (unsigned)__popcll(bal);
    __shared__ unsigned wt[4];
    __shared__ unsigned bbase;
    if (lane == 0) wt[wid] = wtot;
    __syncthreads();
    if (threadIdx.x == 0)
        bbase = atomicAdd(cnt, wt[0] + wt[1] + wt[2] + wt[3]);
    __syncthreads();
    unsigned base = bbase;
    for (int k = 0; k < wid; ++k) base += wt[k];
    if (m) list[base + pre] = i;
}

// ---------------- main: persistent blocks, double-buffered staging ---------
__global__ __launch_bounds__(256, 4)
void flow_mse_main(const float* __restrict__ outp,
                   const float* __restrict__ raw,
                   const int* __restrict__ list,
                   const unsigned int* __restrict__ cntp,
                   float* __restrict__ partial) {
    __shared__ float lds[2 * BUF];        // 27648 B
    __shared__ float sdata[4];
    const int tid = threadIdx.x;
    const int cnt = (int)*cntp;

    float4 st[4];
    int    loff[4];
    float2 fc0, fc1, fn0, fn1;
    TokGeo gc, gn;
    float acc = 0.f;

    int idx = blockIdx.x;
    int cur = 0;

    if (idx < cnt) {                      // prologue: stage first token
        int tk = list[idx];
        gc = geo(tk);
        stage_issue(raw, gc, tid, st, loff);
        const float2* fp = (const float2*)(outp + (size_t)tk * Dd);
        fc0 = fp[tid]; fc1 = fp[256 + tid];
        stage_commit(lds, st, loff);
    }

    while (idx < cnt) {                   // block-uniform condition
        int nidx = idx + GRID_MAIN;
        __syncthreads();                  // buffer `cur` staged & visible
        bool have_next = nidx < cnt;      // block-uniform
        if (have_next) {
            int ntk = list[nidx];
            gn = geo(ntk);
            stage_issue(raw, gn, tid, st, loff);      // loads outstanding...
            const float2* fp = (const float2*)(outp + (size_t)ntk * Dd);
            fn0 = fp[tid]; fn1 = fp[256 + tid];
        }
        acc += compute_tok(raw, lds + cur * BUF, gc, tid, fc0, fc1);  // ...during compute
        if (have_next)
            stage_commit(lds + (cur ^ 1) * BUF, st, loff);
        idx = nidx; cur ^= 1;
        gc = gn; fc0 = fn0; fc1 = fn1;
    }

    // block reduce: 4 waves of 64
    for (int off = 32; off > 0; off >>= 1) acc += __shfl_down(acc, off, 64);
    if ((tid & 63) == 0) sdata[tid >> 6] = acc;
    __syncthreads();
    if (tid == 0)
        partial[blockIdx.x] = sdata[0] + sdata[1] + sdata[2] + sdata[3];
}

// ---------------- finalize: reduce partials + mask count ----------------
__global__ void finalize_kernel(const float* __restrict__ partial,
                                const int* __restrict__ mask,
                                float* __restrict__ out) {
    double s = 0.0;
    for (int i = threadIdx.x; i < GRID_MAIN; i += blockDim.x)
        s += (double)partial[i];
    int cnt = 0;
    for (int i = threadIdx.x; i < MASK_N; i += blockDim.x)
        cnt += (mask[i] != 0) ? 1 : 0;
    for (int off = 32; off > 0; off >>= 1) {
        s   += __shfl_down(s, off, 64);
        cnt += __shfl_down(cnt, off, 64);
    }
    __shared__ double sdat[4];
    __shared__ int    cdat[4];
    int lane = threadIdx.x & 63, wid = threadIdx.x >> 6;
    if (lane == 0) { sdat[wid] = s; cdat[wid] = cnt; }
    __syncthreads();
    if (threadIdx.x == 0) {
        double st = sdat[0] + sdat[1] + sdat[2] + sdat[3];
        int ct = cdat[0] + cdat[1] + cdat[2] + cdat[3];
        double denom = (double)(ct > 0 ? ct : 1) * PATCH_ELEMS;
        out[0] = (float)(st / denom);
    }
}

extern "C" void kernel_launch(void* const* d_in, const int* in_sizes, int n_in,
                              void* d_out, int out_size, void* d_ws, size_t ws_size,
                              hipStream_t stream) {
    const float* outp = (const float*)d_in[0];   // (B,N,D) fp32
    const float* raw  = (const float*)d_in[1];   // (B,C,T,H,W) fp32
    const int*   mask = (const int*)d_in[2];     // (B,N)
    float* out = (float*)d_out;

    // ws layout: [0,16) cnt (+pad) | partial[GRID_MAIN] | list[MASK_N]
    unsigned int* cnt = (unsigned int*)d_ws;
    float* partial = (float*)((char*)d_ws + 16);
    int*   list    = (int*)((char*)d_ws + 16 + GRID_MAIN * 4);

    hipMemsetAsync(d_ws, 0, 16, stream);         // zero the atomic counter

    compact_kernel<<<(MASK_N + 255) / 256, 256, 0, stream>>>(mask, list, cnt);
    flow_mse_main<<<GRID_MAIN, 256, 0, stream>>>(outp, raw, list, cnt, partial);
    finalize_kernel<<<1, 256, 0, stream>>>(partial, mask, out);
}

// Round 6
// 169.980 us; speedup vs baseline: 1.1834x; 1.1834x over previous
//
#include <hip/hip_runtime.h>

// Problem constants: B=8, C=3, T=16, H=W=224, P0=2, P=16, FC=2
#define Bd 8
#define Cd 3
#define Td 16
#define Hd 224
#define Wd 224
#define Nd 1568            // (T/2)*(H/16)*(W/16)
#define Dd 1024            // 2*16*16*2
#define HWd (Hd*Wd)        // 50176
#define MASK_N (Bd*Nd)     // 12544
#define PATCH_ELEMS 1536.0

#define WIN 24             // 16x16 patch + 4 halo each side
#define PITCH 24           // contiguous plane: rows 96 B apart, float4-aligned
#define PLANE (WIN*PITCH)  // 576 floats
#define BUF (6*PLANE)      // 3456 floats (13824 B) per double-buffer half
#define GRID_MAIN 1024
#define STG_V4 864         // 6 planes * 24 rows * 6 float4/row

struct TokGeo { int b, t2, ph, pw, WX, WY; };

__device__ __forceinline__ TokGeo geo(int tk) {
    TokGeo g;
    g.b = tk / Nd;
    int n = tk - g.b * Nd;
    g.t2 = n / 196;
    int rem = n - g.t2 * 196;
    g.ph = rem / 14;
    g.pw = rem - g.ph * 14;
    g.WX = min(max(g.pw * 16 - 4, 0), Wd - WIN);
    g.WY = min(max(g.ph * 16 - 4, 0), Hd - WIN);
    return g;
}

// decompose staging index j -> (lds float-offset, global float-offset rel. to
// token window origin). Token-invariant: computed once per thread.
__device__ __forceinline__ void stg_geom(int j, int& ldsoff, int& goff) {
    int p   = j / 144;                 // plane = c*2 + i0
    int rem = j - p * 144;
    int r   = rem / 6;
    int c4  = (rem - r * 6) << 2;
    ldsoff = p * PLANE + r * PITCH + c4;
    goff   = (p >> 1) * (16 * HWd) + (p & 1) * HWd + r * Wd + c4;
}

__device__ __forceinline__ float compute_tok(const float* __restrict__ raw,
                                             const float* __restrict__ pl0,
                                             const TokGeo& g, int tid,
                                             float2 f0, float2 f1) {
    const int i1 = tid >> 4, i2 = tid & 15;
    const int h = (g.ph << 4) + i1;
    const int w = (g.pw << 4) + i2;
    const int tIdx = (h - g.WY) * PITCH + (w - g.WX);
    float acc = 0.f;
    #pragma unroll
    for (int i0 = 0; i0 < 2; ++i0) {
        float2 f = i0 ? f1 : f0;
        float mx = f.x + (float)w;
        float my = f.y + (float)h;

        float x0 = floorf(mx), y0 = floorf(my);
        float wx = mx - x0,    wy = my - y0;
        int x0i = (int)x0, y0i = (int)y0;
        int x1i = x0i + 1, y1i = y0i + 1;

        bool vx0 = (x0i >= 0) && (x0i < Wd);
        bool vx1 = (x1i >= 0) && (x1i < Wd);
        bool vy0 = (y0i >= 0) && (y0i < Hd);
        bool vy1 = (y1i >= 0) && (y1i < Hd);

        int xc0 = min(max(x0i, 0), Wd - 1);
        int xc1 = min(max(x1i, 0), Wd - 1);
        int yc0 = min(max(y0i, 0), Hd - 1);
        int yc1 = min(max(y1i, 0), Hd - 1);

        float w00 = (1.f - wx) * (1.f - wy) * ((vx0 && vy0) ? 1.f : 0.f);
        float w01 = wx         * (1.f - wy) * ((vx1 && vy0) ? 1.f : 0.f);
        float w10 = (1.f - wx) * wy         * ((vx0 && vy1) ? 1.f : 0.f);
        float w11 = wx         * wy         * ((vx1 && vy1) ? 1.f : 0.f);

        const int lx0 = xc0 - g.WX, lx1 = xc1 - g.WX;
        const int ly0 = yc0 - g.WY, ly1 = yc1 - g.WY;
        const bool ok = (lx0 >= 0) & (lx1 < WIN) & (ly0 >= 0) & (ly1 < WIN);

        if (ok) {
            const int b00 = ly0 * PITCH + lx0;
            const int b01 = ly0 * PITCH + lx1;
            const int b10 = ly1 * PITCH + lx0;
            const int b11 = ly1 * PITCH + lx1;
            #pragma unroll
            for (int c = 0; c < Cd; ++c) {
                const float* pl = pl0 + ((c << 1) | i0) * PLANE;
                float rec = pl[b00] * w00 + pl[b01] * w01
                          + pl[b10] * w10 + pl[b11] * w11;
                float d = rec - pl[tIdx];
                acc += d * d;
            }
        } else {   // sample escaped +-4 halo: P ~ 6e-5, execz-skipped usually
            const int i00 = yc0 * Wd + xc0;
            const int i01 = yc0 * Wd + xc1;
            const int i10 = yc1 * Wd + xc0;
            const int i11 = yc1 * Wd + xc1;
            const float* base = raw + ((size_t)g.b * 48 + (size_t)g.t2 * 2 + i0) * HWd;
            #pragma unroll
            for (int c = 0; c < Cd; ++c) {
                const float* img = base + c * (16 * HWd);
                float rec = img[i00] * w00 + img[i01] * w01
                          + img[i10] * w10 + img[i11] * w11;
                const float* pl = pl0 + ((c << 1) | i0) * PLANE;
                float d = rec - pl[tIdx];
                acc += d * d;
            }
        }
    }
    return acc;
}

// ---------------- compaction: active token list ----------------
__global__ void compact_kernel(const int* __restrict__ mask,
                               int* __restrict__ list,
                               unsigned int* __restrict__ cnt) {
    int i = blockIdx.x * 256 + threadIdx.x;
    bool m = (i < MASK_N) && (mask[i] != 0);
    unsigned long long bal = __ballot(m);
    int lane = threadIdx.x & 63;
    int wid  = threadIdx.x >> 6;
    unsigned pre  = (unsigned)__popcll(bal & ((1ull << lane) - 1ull));
    unsigned wtot = (unsigned)__popcll(bal);
    __shared__ unsigned wt[4];
    __shared__ unsigned bbase;
    if (lane == 0) wt[wid] = wtot;
    __syncthreads();
    if (threadIdx.x == 0)
        bbase = atomicAdd(cnt, wt[0] + wt[1] + wt[2] + wt[3]);
    __syncthreads();
    unsigned base = bbase;
    for (int k = 0; k < wid; ++k) base += wt[k];
    if (m) list[base + pre] = i;
}

// ---------------- main: persistent blocks, double-buffered staging ---------
// Staging data held in NAMED float4 scalars (no arrays -> no scratch spill).
__global__ __launch_bounds__(256, 4)
void flow_mse_main(const float* __restrict__ outp,
                   const float* __restrict__ raw,
                   const int* __restrict__ list,
                   const unsigned int* __restrict__ cntp,
                   float* __restrict__ partial) {
    __shared__ float lds[2 * BUF];        // 27648 B
    __shared__ float sdata[4];
    const int tid = threadIdx.x;
    const int cnt = (int)*cntp;

    // token-invariant staging geometry (k=0..2 always valid; k=3 iff tid<96)
    int l0, l1, l2, l3, q0, q1, q2, q3;
    stg_geom(tid,       l0, q0);
    stg_geom(tid + 256, l1, q1);
    stg_geom(tid + 512, l2, q2);
    const bool k3 = tid < (STG_V4 - 768);
    stg_geom(k3 ? tid + 768 : 0, l3, q3);

    float4 s0, s1, s2, s3;
    float2 fc0, fc1, fn0, fn1;
    TokGeo gc, gn;
    float acc = 0.f;

    int idx = blockIdx.x;
    int cur = 0;

    if (idx < cnt) {                      // prologue: stage first token
        int tk = list[idx];
        gc = geo(tk);
        const float* base = raw + ((size_t)gc.b * 48 + (size_t)gc.t2 * 2) * HWd
                          + gc.WY * Wd + gc.WX;
        s0 = *(const float4*)(base + q0);
        s1 = *(const float4*)(base + q1);
        s2 = *(const float4*)(base + q2);
        if (k3) s3 = *(const float4*)(base + q3);
        const float2* fp = (const float2*)(outp + (size_t)tk * Dd);
        fc0 = fp[tid]; fc1 = fp[256 + tid];
        *(float4*)(lds + l0) = s0;
        *(float4*)(lds + l1) = s1;
        *(float4*)(lds + l2) = s2;
        if (k3) *(float4*)(lds + l3) = s3;
    }

    while (idx < cnt) {                   // block-uniform condition
        int nidx = idx + GRID_MAIN;
        __syncthreads();                  // buffer `cur` staged & visible
        bool have_next = nidx < cnt;      // block-uniform
        if (have_next) {
            int ntk = list[nidx];
            gn = geo(ntk);
            const float* base = raw + ((size_t)gn.b * 48 + (size_t)gn.t2 * 2) * HWd
                              + gn.WY * Wd + gn.WX;
            s0 = *(const float4*)(base + q0);          // loads outstanding...
            s1 = *(const float4*)(base + q1);
            s2 = *(const float4*)(base + q2);
            if (k3) s3 = *(const float4*)(base + q3);
            const float2* fp = (const float2*)(outp + (size_t)ntk * Dd);
            fn0 = fp[tid]; fn1 = fp[256 + tid];
        }
        acc += compute_tok(raw, lds + cur * BUF, gc, tid, fc0, fc1);  // ...during compute
        if (have_next) {
            float* dst = lds + (cur ^ 1) * BUF;
            *(float4*)(dst + l0) = s0;
            *(float4*)(dst + l1) = s1;
            *(float4*)(dst + l2) = s2;
            if (k3) *(float4*)(dst + l3) = s3;
        }
        idx = nidx; cur ^= 1;
        gc = gn; fc0 = fn0; fc1 = fn1;
    }

    // block reduce: 4 waves of 64
    for (int off = 32; off > 0; off >>= 1) acc += __shfl_down(acc, off, 64);
    if ((tid & 63) == 0) sdata[tid >> 6] = acc;
    __syncthreads();
    if (tid == 0)
        partial[blockIdx.x] = sdata[0] + sdata[1] + sdata[2] + sdata[3];
}

// ---------------- finalize: reduce partials + mask count ----------------
__global__ void finalize_kernel(const float* __restrict__ partial,
                                const int* __restrict__ mask,
                                float* __restrict__ out) {
    double s = 0.0;
    for (int i = threadIdx.x; i < GRID_MAIN; i += blockDim.x)
        s += (double)partial[i];
    int cnt = 0;
    for (int i = threadIdx.x; i < MASK_N; i += blockDim.x)
        cnt += (mask[i] != 0) ? 1 : 0;
    for (int off = 32; off > 0; off >>= 1) {
        s   += __shfl_down(s, off, 64);
        cnt += __shfl_down(cnt, off, 64);
    }
    __shared__ double sdat[4];
    __shared__ int    cdat[4];
    int lane = threadIdx.x & 63, wid = threadIdx.x >> 6;
    if (lane == 0) { sdat[wid] = s; cdat[wid] = cnt; }
    __syncthreads();
    if (threadIdx.x == 0) {
        double st = sdat[0] + sdat[1] + sdat[2] + sdat[3];
        int ct = cdat[0] + cdat[1] + cdat[2] + cdat[3];
        double denom = (double)(ct > 0 ? ct : 1) * PATCH_ELEMS;
        out[0] = (float)(st / denom);
    }
}

extern "C" void kernel_launch(void* const* d_in, const int* in_sizes, int n_in,
                              void* d_out, int out_size, void* d_ws, size_t ws_size,
                              hipStream_t stream) {
    const float* outp = (const float*)d_in[0];   // (B,N,D) fp32
    const float* raw  = (const float*)d_in[1];   // (B,C,T,H,W) fp32
    const int*   mask = (const int*)d_in[2];     // (B,N)
    float* out = (float*)d_out;

    // ws layout: [0,16) cnt | partial[GRID_MAIN] | list[MASK_N]
    unsigned int* cnt = (unsigned int*)d_ws;
    float* partial = (float*)((char*)d_ws + 16);
    int*   list    = (int*)((char*)d_ws + 16 + GRID_MAIN * 4);

    hipMemsetAsync(d_ws, 0, 16, stream);

    compact_kernel<<<(MASK_N + 255) / 256, 256, 0, stream>>>(mask, list, cnt);
    flow_mse_main<<<GRID_MAIN, 256, 0, stream>>>(outp, raw, list, cnt, partial);
    finalize_kernel<<<1, 256, 0, stream>>>(partial, mask, out);
}